// Round 4
// baseline (156.847 us; speedup 1.0000x reference)
//
#include <hip/hip_runtime.h>
#include <hip/hip_bf16.h>

// Problem constants: B=128 targets, N=50000 data, D=384, DO=2048, K=10.
#define DIM   384
#define DIMO  2048
#define KNN   10
#define KSEL  16
#define FINF  3.0e38f
#define BK    64
#define PITCH 72   // bf16 elems per LDS row: 64 data + 8 pad

typedef __attribute__((ext_vector_type(8))) short short8v;
typedef __attribute__((ext_vector_type(4))) float float4v;

__device__ __forceinline__ unsigned short f2bf(float x) {
    // scalar cast -> compiler emits v_cvt_pk_bf16_f32 pairs (RNE)
    return __bfloat16_as_ushort(__float2bfloat16(x));
}

// -------------------------------------------------------------------------
// Kernel 1: bf16-MFMA approx score + per-block per-row top-10 candidates.
// approx_score[m][n] = ||d_n||^2 (exact f32) - 2 * bf16dot(t_m, d_n).
// Tile: 128 targets x 128 data cols, BK=64, 4 waves in 2x2, each wave a
// 64x64 sub-tile of 4x4 16x16x32-bf16 fragments.   (unchanged from R3)
// -------------------------------------------------------------------------
__global__ __launch_bounds__(256) void score_topk_kernel(
    const float* __restrict__ tgt,     // [128][384]
    const float* __restrict__ dat,     // [N][384]
    float* __restrict__ cand_s,        // [128][nblk*10]
    int*   __restrict__ cand_i,        // [128][nblk*10]
    int N, int nblk)
{
    __shared__ unsigned short tAB[2 * 128 * PITCH];           // 36 KB
    unsigned short* tA = tAB;
    unsigned short* tB = tAB + 128 * PITCH;
    float (*sc)[129] = reinterpret_cast<float(*)[129]>(tAB);  // 33 KB overlay
    __shared__ float d2p[128][8];
    __shared__ float d2s[128];

    const int tid   = threadIdx.x;
    const int nbase = blockIdx.x * 128;
    const int lane  = tid & 63;
    const int wv    = tid >> 6;
    const int wr    = wv >> 1;
    const int wc    = wv & 1;
    const int r0    = tid >> 3;
    const int c8    = tid & 7;

    const int frow  = lane & 15;
    const int kg    = lane >> 4;

    float4v acc[4][4];
#pragma unroll
    for (int i = 0; i < 4; ++i)
#pragma unroll
        for (int j = 0; j < 4; ++j) acc[i][j] = (float4v){0.f, 0.f, 0.f, 0.f};

    float d2acc[4] = {0.f, 0.f, 0.f, 0.f};

    for (int k0 = 0; k0 < DIM; k0 += BK) {
        __syncthreads();
#pragma unroll
        for (int it = 0; it < 4; ++it) {
            int row = it * 32 + r0;
            const float* s = &tgt[row * DIM + k0 + c8 * 8];
            float4 u0 = *reinterpret_cast<const float4*>(s);
            float4 u1 = *reinterpret_cast<const float4*>(s + 4);
            short8v h;
            h[0] = (short)f2bf(u0.x); h[1] = (short)f2bf(u0.y);
            h[2] = (short)f2bf(u0.z); h[3] = (short)f2bf(u0.w);
            h[4] = (short)f2bf(u1.x); h[5] = (short)f2bf(u1.y);
            h[6] = (short)f2bf(u1.z); h[7] = (short)f2bf(u1.w);
            *reinterpret_cast<short8v*>(&tA[row * PITCH + c8 * 8]) = h;
        }
#pragma unroll
        for (int it = 0; it < 4; ++it) {
            int row = it * 32 + r0;
            int g   = nbase + row;
            float4 u0 = make_float4(0.f, 0.f, 0.f, 0.f);
            float4 u1 = make_float4(0.f, 0.f, 0.f, 0.f);
            if (g < N) {
                const float* s = &dat[(size_t)g * DIM + k0 + c8 * 8];
                u0 = *reinterpret_cast<const float4*>(s);
                u1 = *reinterpret_cast<const float4*>(s + 4);
            }
            d2acc[it] += u0.x * u0.x + u0.y * u0.y + u0.z * u0.z + u0.w * u0.w
                       + u1.x * u1.x + u1.y * u1.y + u1.z * u1.z + u1.w * u1.w;
            short8v h;
            h[0] = (short)f2bf(u0.x); h[1] = (short)f2bf(u0.y);
            h[2] = (short)f2bf(u0.z); h[3] = (short)f2bf(u0.w);
            h[4] = (short)f2bf(u1.x); h[5] = (short)f2bf(u1.y);
            h[6] = (short)f2bf(u1.z); h[7] = (short)f2bf(u1.w);
            *reinterpret_cast<short8v*>(&tB[row * PITCH + c8 * 8]) = h;
        }
        __syncthreads();
#pragma unroll
        for (int ks = 0; ks < 2; ++ks) {
            short8v a[4], b[4];
            const int koff = ks * 32 + kg * 8;
#pragma unroll
            for (int f = 0; f < 4; ++f) {
                a[f] = *reinterpret_cast<const short8v*>(
                    &tA[(wr * 64 + f * 16 + frow) * PITCH + koff]);
                b[f] = *reinterpret_cast<const short8v*>(
                    &tB[(wc * 64 + f * 16 + frow) * PITCH + koff]);
            }
#pragma unroll
            for (int fr = 0; fr < 4; ++fr)
#pragma unroll
                for (int fc = 0; fc < 4; ++fc)
                    acc[fr][fc] = __builtin_amdgcn_mfma_f32_16x16x32_bf16(
                        a[fr], b[fc], acc[fr][fc], 0, 0, 0);
        }
    }

    __syncthreads();
#pragma unroll
    for (int it = 0; it < 4; ++it) d2p[it * 32 + r0][c8] = d2acc[it];
    __syncthreads();
    if (tid < 128) {
        float s = 0.f;
#pragma unroll
        for (int j = 0; j < 8; ++j) s += d2p[tid][j];
        d2s[tid] = s;
    }

    const int M = nblk * KNN;
    for (int h = 0; h < 2; ++h) {
        __syncthreads();
        if (wr == h) {
#pragma unroll
            for (int fr = 0; fr < 4; ++fr)
#pragma unroll
                for (int fc = 0; fc < 4; ++fc)
#pragma unroll
                    for (int e = 0; e < 4; ++e) {
                        int lr = fr * 16 + kg * 4 + e;
                        int lc = wc * 64 + fc * 16 + frow;
                        int n  = nbase + lc;
                        sc[lr][lc] = (n < N) ? d2s[lc] - 2.f * acc[fr][fc][e]
                                             : FINF;
                    }
        }
        __syncthreads();
        if (tid < 64) {
            int grow = h * 64 + tid;
            float ts[KNN];
            int   ti[KNN];
#pragma unroll
            for (int k = 0; k < KNN; ++k) { ts[k] = FINF; ti[k] = 0x7fffffff; }
            for (int c = 0; c < 128; ++c) {
                float s = sc[tid][c];
                if (s < ts[KNN - 1]) {
                    ts[KNN - 1] = s;
                    ti[KNN - 1] = nbase + c;
#pragma unroll
                    for (int p = KNN - 1; p > 0; --p) {
                        if (ts[p] < ts[p - 1]) {
                            float fs = ts[p]; ts[p] = ts[p - 1]; ts[p - 1] = fs;
                            int   fi = ti[p]; ti[p] = ti[p - 1]; ti[p - 1] = fi;
                        }
                    }
                }
            }
            size_t base = (size_t)grow * M + (size_t)blockIdx.x * KNN;
#pragma unroll
            for (int k = 0; k < KNN; ++k) {
                cand_s[base + k] = ts[k];
                cand_i[base + k] = ti[k];
            }
        }
    }
}

// -------------------------------------------------------------------------
// Kernel 2: merge candidates -> approx top-16 via barrier-free shuffle
// tournament, exact-f32 rescore (bit-identical to R1/R3 arithmetic),
// select top-10, and gather OTinput/OToutput rows. One block per target.
// -------------------------------------------------------------------------
__global__ __launch_bounds__(256) void select_rescore_gather_kernel(
    const float* __restrict__ cand_s,  // [B][M]
    const int*   __restrict__ cand_i,  // [B][M]
    const float* __restrict__ tgt,     // [128][384]
    const float* __restrict__ dat,     // [N][384]
    const float* __restrict__ OTin,    // [N][384]
    const float* __restrict__ OTout,   // [N][2048]
    float* __restrict__ out,           // [B*10*384] ++ [B*10*2048]
    int M, int B)
{
    const int b    = blockIdx.x;
    const int tid  = threadIdx.x;
    const int lane = tid & 63;
    const int wv   = tid >> 6;
    const float* rs_ = cand_s + (size_t)b * M;
    const int*   ri_ = cand_i + (size_t)b * M;

    // ---- per-thread sorted top-16 (lex (score, idx)) — static indexing ----
    float ts[KSEL];
    int   ti[KSEL];
#pragma unroll
    for (int k = 0; k < KSEL; ++k) { ts[k] = FINF; ti[k] = 0x7fffffff; }

    for (int j = tid; j < M; j += 256) {
        float s  = rs_[j];
        int   id = ri_[j];
        if (s < ts[KSEL - 1] || (s == ts[KSEL - 1] && id < ti[KSEL - 1])) {
            ts[KSEL - 1] = s;
            ti[KSEL - 1] = id;
#pragma unroll
            for (int p = KSEL - 1; p > 0; --p) {
                bool sw = (ts[p] < ts[p - 1]) ||
                          (ts[p] == ts[p - 1] && ti[p] < ti[p - 1]);
                if (sw) {
                    float fs = ts[p]; ts[p] = ts[p - 1]; ts[p - 1] = fs;
                    int   fi = ti[p]; ti[p] = ti[p - 1]; ti[p - 1] = fi;
                }
            }
        }
    }

    // LDS: per-thread sorted lists (for dynamic head pops) + wave winners
    __shared__ float ls[256 * KSEL];   // 16 KB
    __shared__ int   li[256 * KSEL];   // 16 KB
    __shared__ float wout_s[4 * KSEL];
    __shared__ int   wout_i[4 * KSEL];
    __shared__ int   sel16[KSEL];
    __shared__ float ex_s[KSEL];
    __shared__ int   ex_i[KSEL];
    __shared__ int   selk[KNN];

#pragma unroll
    for (int k = 0; k < KSEL; ++k) {
        ls[tid * KSEL + k] = ts[k];
        li[tid * KSEL + k] = ti[k];
    }
    // (each lane only reads its own list slots — no barrier needed)

    // ---- phase B: per-wave 64-list tournament of heads (no barriers) ----
    {
        int   hp = 0;
        float hs = ts[0];
        int   hi = ti[0];
#pragma unroll
        for (int k = 0; k < KSEL; ++k) {
            float ms = hs; int mi = hi;
#pragma unroll
            for (int m = 32; m > 0; m >>= 1) {
                float s2 = __shfl_xor(ms, m);
                int   i2 = __shfl_xor(mi, m);
                if (s2 < ms || (s2 == ms && i2 < mi)) { ms = s2; mi = i2; }
            }
            if (lane == 0) { wout_s[wv * KSEL + k] = ms; wout_i[wv * KSEL + k] = mi; }
            bool iwin = (hs == ms) && (hi == mi);   // candidates unique -> unique winner
            if (iwin) {
                if (hp < KSEL - 1) {
                    ++hp;
                    hs = ls[tid * KSEL + hp];
                    hi = li[tid * KSEL + hp];
                } else {
                    hs = FINF; hi = 0x7fffffff;
                }
            }
        }
    }
    __syncthreads();

    // ---- phase C: wave 0 merges 4x16 winners (64 lanes, 1 each) ----
    if (wv == 0) {
        float s = wout_s[lane];
        int   i = wout_i[lane];
#pragma unroll
        for (int k = 0; k < KSEL; ++k) {
            float ms = s; int mi = i;
#pragma unroll
            for (int m = 32; m > 0; m >>= 1) {
                float s2 = __shfl_xor(ms, m);
                int   i2 = __shfl_xor(mi, m);
                if (s2 < ms || (s2 == ms && i2 < mi)) { ms = s2; mi = i2; }
            }
            if (lane == 0) sel16[k] = mi;
            if (s == ms && i == mi) { s = FINF; i = 0x7fffffff; }
        }
    }
    __syncthreads();

    // ---- exact f32 rescore (bit-identical to R1 arithmetic) ----
    if (tid < KSEL) {
        const int n = sel16[tid];
        float d2p_[8] = {0.f, 0.f, 0.f, 0.f, 0.f, 0.f, 0.f, 0.f};
        float dot = 0.f;
        for (int c = 0; c < DIM / 32; ++c) {
#pragma unroll
            for (int j = 0; j < 8; ++j) {
                const float4 v = *reinterpret_cast<const float4*>(
                    &dat[(size_t)n * DIM + c * 32 + j * 4]);
                const float4 t = *reinterpret_cast<const float4*>(
                    &tgt[(size_t)b * DIM + c * 32 + j * 4]);
                d2p_[j] += v.x * v.x + v.y * v.y + v.z * v.z + v.w * v.w;
                dot = fmaf(t.x, v.x, dot);
                dot = fmaf(t.y, v.y, dot);
                dot = fmaf(t.z, v.z, dot);
                dot = fmaf(t.w, v.w, dot);
            }
        }
        float d2 = 0.f;
#pragma unroll
        for (int j = 0; j < 8; ++j) d2 += d2p_[j];
        ex_s[tid] = d2 - 2.f * dot;
        ex_i[tid] = n;
    }
    __syncthreads();

    // ---- final top-10 by (exact score, idx) ----
    if (tid == 0) {
        float fs[KNN]; int fi[KNN];
#pragma unroll
        for (int k = 0; k < KNN; ++k) { fs[k] = FINF; fi[k] = 0x7fffffff; }
        for (int q = 0; q < KSEL; ++q) {
            float s  = ex_s[q];
            int   id = ex_i[q];
            if (s < fs[KNN - 1] || (s == fs[KNN - 1] && id < fi[KNN - 1])) {
                fs[KNN - 1] = s;
                fi[KNN - 1] = id;
#pragma unroll
                for (int p = KNN - 1; p > 0; --p) {
                    bool sw = (fs[p] < fs[p - 1]) ||
                              (fs[p] == fs[p - 1] && fi[p] < fi[p - 1]);
                    if (sw) {
                        float a = fs[p]; fs[p] = fs[p - 1]; fs[p - 1] = a;
                        int   i2 = fi[p]; fi[p] = fi[p - 1]; fi[p - 1] = i2;
                    }
                }
            }
        }
#pragma unroll
        for (int k = 0; k < KNN; ++k) selk[k] = fi[k];
    }
    __syncthreads();

    // ---- fused gather: 10 x (384 + 2048) f32 rows, float4 coalesced ----
    const size_t o1 = (size_t)B * KNN * DIM;
    const float4* in4  = reinterpret_cast<const float4*>(OTin);
    const float4* ino4 = reinterpret_cast<const float4*>(OTout);
    float4* out4  = reinterpret_cast<float4*>(out);
    float4* outo4 = reinterpret_cast<float4*>(out + o1);

    for (int q = tid; q < KNN * (DIM / 4); q += 256) {
        int k = q / (DIM / 4);
        int c = q - k * (DIM / 4);
        int idx = selk[k];
        out4[((size_t)b * KNN + k) * (DIM / 4) + c] =
            in4[(size_t)idx * (DIM / 4) + c];
    }
    for (int q = tid; q < KNN * (DIMO / 4); q += 256) {
        int k = q / (DIMO / 4);
        int c = q - k * (DIMO / 4);
        int idx = selk[k];
        outo4[((size_t)b * KNN + k) * (DIMO / 4) + c] =
            ino4[(size_t)idx * (DIMO / 4) + c];
    }
}

extern "C" void kernel_launch(void* const* d_in, const int* in_sizes, int n_in,
                              void* d_out, int out_size, void* d_ws, size_t ws_size,
                              hipStream_t stream) {
    const float* targets = (const float*)d_in[0];
    const float* data    = (const float*)d_in[1];
    const float* OTin    = (const float*)d_in[2];
    const float* OTout   = (const float*)d_in[3];
    float* out = (float*)d_out;

    const int B = in_sizes[0] / DIM;   // 128
    const int N = in_sizes[1] / DIM;   // 50000

    const int nblk = (N + 127) / 128;  // 391
    const int M    = nblk * KNN;       // 3910

    float* cand_s = (float*)d_ws;                       // B*M floats
    int*   cand_i = (int*)(cand_s + (size_t)B * M);     // B*M ints

    score_topk_kernel<<<nblk, 256, 0, stream>>>(targets, data, cand_s, cand_i, N, nblk);
    select_rescore_gather_kernel<<<B, 256, 0, stream>>>(
        cand_s, cand_i, targets, data, OTin, OTout, out, M, B);
}